// Round 1
// 2437.390 us; speedup vs baseline: 1.0127x; 1.0127x over previous
//
#include <hip/hip_runtime.h>
#include <hip/hip_bf16.h>

// Problem: N=128 nodes, T=512, I=32, H=256, 2-layer per-node LSTM + LayerNorm.
// Inputs (fp32): x, Wih0, Whh0, bih0, bhh0, Wih1, Whh1, bih1, bhh1, gamma, beta
// Output (fp32): LN(h_last of layer 1), shape (128, 256).

typedef _Float16 half2_t __attribute__((ext_vector_type(2)));
typedef _Float16 half8_t __attribute__((ext_vector_type(8)));
typedef float floatx4 __attribute__((ext_vector_type(4)));

__device__ __forceinline__ unsigned pk(float a, float b) {
  half2_t h = { (_Float16)a, (_Float16)b };
  return __builtin_bit_cast(unsigned, h);
}
__device__ __forceinline__ float fdot2(unsigned w, unsigned h, float c) {
  return __builtin_amdgcn_fdot2(__builtin_bit_cast(half2_t, w),
                                __builtin_bit_cast(half2_t, h), c, false);
}
__device__ __forceinline__ float h2f(unsigned short u) {
  return (float)__builtin_bit_cast(_Float16, u);
}
__device__ __forceinline__ unsigned short f2h(float f) {
  return __builtin_bit_cast(unsigned short, (_Float16)f);
}
__device__ __forceinline__ float sigmf(float x) {
  return __builtin_amdgcn_rcpf(1.f + __expf(-x));
}
__device__ __forceinline__ float tanh_(float x) {
  return 2.f * sigmf(2.f * x) - 1.f;
}
__device__ __forceinline__ floatx4 mfma16(half8_t a, half8_t b, floatx4 c) {
  return __builtin_amdgcn_mfma_f32_16x16x32_f16(a, b, c, 0, 0, 0);
}
// v_readlane_b32: broadcast lane l of a VGPR into an SGPR (VALU pipe, no LDS).
__device__ __forceinline__ unsigned rlane(unsigned v, int l) {
  return (unsigned)__builtin_amdgcn_readlane((int)v, l);
}

// ---------------------------------------------------------------------------
// GEMM: C[n][m][g] = sum_k A[n][m][k] * B[n][g][k], C stored f16.
// M=512 (time), N=1024 (gates), per-node batched. B always fp32 (torch weights).
// A fp32 (layer0: x, K=32) or f16 (layer1: hs0, K=256).
// 128x128 tiles, 4 waves in 2x2, each wave 64x64 via 4x4 mfma_f32_16x16x32_f16.
// ---------------------------------------------------------------------------
template<int K, int KT, bool AF16>
__global__ __launch_bounds__(256)
void gemm_xw(const void* __restrict__ Ap, const float* __restrict__ Bp,
             unsigned short* __restrict__ Cp)
{
  __shared__ unsigned short As[128][KT + 8];
  __shared__ unsigned short Bs[128][KT + 8];
  const int tid = threadIdx.x;
  const int node = blockIdx.y;
  const int mt = blockIdx.x >> 3;   // 4 m-tiles
  const int nt = blockIdx.x & 7;    // 8 n-tiles
  const int lane = tid & 63, wv = tid >> 6;
  const int wr = wv >> 1, wc = wv & 1;
  const int lm = lane & 15, lk = (lane >> 4) * 8;

  floatx4 zero = {0.f, 0.f, 0.f, 0.f};
  floatx4 acc[4][4];
#pragma unroll
  for (int i = 0; i < 4; ++i)
#pragma unroll
    for (int j = 0; j < 4; ++j) acc[i][j] = zero;

  for (int kt = 0; kt < K; kt += KT) {
    if (AF16) {
      const unsigned short* A = (const unsigned short*)Ap + (size_t)node * 512 * K;
      const int CPR = KT / 8;  // 16B chunks per row
#pragma unroll
      for (int c = tid; c < 128 * CPR; c += 256) {
        int r = c / CPR, cc = (c % CPR) * 8;
        *(uint4*)&As[r][cc] =
            *(const uint4*)(A + (size_t)(mt * 128 + r) * K + kt + cc);
      }
    } else {
      const float* A = (const float*)Ap + (size_t)node * 512 * K;
      const int CPR = KT / 4;
#pragma unroll
      for (int c = tid; c < 128 * CPR; c += 256) {
        int r = c / CPR, cc = (c % CPR) * 4;
        float4 v = *(const float4*)(A + (size_t)(mt * 128 + r) * K + kt + cc);
        uint2 p = make_uint2(pk(v.x, v.y), pk(v.z, v.w));
        *(uint2*)&As[r][cc] = p;
      }
    }
    {
      const float* B = Bp + (size_t)node * 1024 * K;
      const int CPR = KT / 4;
#pragma unroll
      for (int c = tid; c < 128 * CPR; c += 256) {
        int r = c / CPR, cc = (c % CPR) * 4;
        float4 v = *(const float4*)(B + (size_t)(nt * 128 + r) * K + kt + cc);
        uint2 p = make_uint2(pk(v.x, v.y), pk(v.z, v.w));
        *(uint2*)&Bs[r][cc] = p;
      }
    }
    __syncthreads();
#pragma unroll
    for (int ks = 0; ks < KT / 32; ++ks) {
      half8_t af[4], bf[4];
#pragma unroll
      for (int i = 0; i < 4; ++i)
        af[i] = *(const half8_t*)&As[wr * 64 + i * 16 + lm][ks * 32 + lk];
#pragma unroll
      for (int j = 0; j < 4; ++j)
        bf[j] = *(const half8_t*)&Bs[wc * 64 + j * 16 + lm][ks * 32 + lk];
#pragma unroll
      for (int i = 0; i < 4; ++i)
#pragma unroll
        for (int j = 0; j < 4; ++j)
          acc[i][j] = mfma16(af[i], bf[j], acc[i][j]);
    }
    __syncthreads();
  }
  // C/D layout: col = lane&15, row = (lane>>4)*4 + reg (m89/m91-verified)
  unsigned short* C = Cp + (size_t)node * 512 * 1024;
#pragma unroll
  for (int i = 0; i < 4; ++i)
#pragma unroll
    for (int j = 0; j < 4; ++j)
#pragma unroll
      for (int r = 0; r < 4; ++r) {
        int row = mt * 128 + wr * 64 + i * 16 + (lane >> 4) * 4 + r;
        int col = nt * 128 + wc * 64 + j * 16 + lm;
        C[(size_t)row * 1024 + col] = f2h(acc[i][j][r]);
      }
}

// ---------------------------------------------------------------------------
// Persistent per-node LSTM recurrence. One workgroup (512 thr) per node.
// Thread tid owns gate rows g0=tid, g1=tid+512 of Whh (gate order i,f,g,o):
//   tid<256  -> (i_j, g_j), j=tid ; tid>=256 -> (f_j, o_j), j=tid-256.
// Whh rows packed f16: 96 dwords/row in VGPRs + 32 dwords/row in LDS (128 KB).
//
// h broadcast (NEW): instead of 32 wave-uniform ds_read_b128 per wave per
// timestep (LDS-pipe bound: 8 waves x 48 b128 x ~12cyc ~= 4600 cyc/step),
// each wave reads the whole 512B h vector with ONE ds_read_b64 (lane l gets
// h-dwords 2l, 2l+1) and broadcasts each dword into an SGPR via
// v_readlane_b32 (VALU pipe), consumed as the scalar operand of v_dot2.
// Mapping: h-dword d (f16 pair 2d,2d+1) lives at lane d>>1, component d&1.
// ---------------------------------------------------------------------------
#define VWP 96  // weight dwords (f16 pairs) per row held in VGPRs (of 128)

template<bool WRITE_HS, bool FINAL>
__global__ __launch_bounds__(512, 2)
void lstm_rec(const unsigned short* __restrict__ xW,   // [n][t][1024] f16 (no bias)
              const float* __restrict__ Whh,           // [n][1024][256] fp32
              const float* __restrict__ bih, const float* __restrict__ bhh,
              unsigned* __restrict__ hs,               // [n][t][128] f16-pairs (out)
              const float* __restrict__ gamma, const float* __restrict__ beta,
              float* __restrict__ out)                 // [n][256] fp32
{
  __shared__ uint4 lw4[16][512];                       // 128 KB LDS weight slice
  __shared__ __align__(16) unsigned short hbuf[256];   // h as f16
  __shared__ float fBuf[256], oBuf[256];
  __shared__ float redBuf[2];

  const int tid = threadIdx.x;
  const int lane = tid & 63;
  const int n = blockIdx.x;
  const int g0 = tid, g1 = tid + 512;

  const float b0 = bih[n * 1024 + g0] + bhh[n * 1024 + g0];
  const float b1 = bih[n * 1024 + g1] + bhh[n * 1024 + g1];

  // ---- load + convert weights (rows are K-contiguous; L1 line reuse) ----
  const float4* w0p = (const float4*)(Whh + ((size_t)n * 1024 + g0) * 256);
  const float4* w1p = (const float4*)(Whh + ((size_t)n * 1024 + g1) * 256);
  unsigned wv0[VWP], wv1[VWP];
#pragma unroll
  for (int i = 0; i < VWP / 2; ++i) {   // 48 float4 per row -> VGPRs
    float4 v = w0p[i];
    wv0[2 * i] = pk(v.x, v.y);
    wv0[2 * i + 1] = pk(v.z, v.w);
    float4 u = w1p[i];
    wv1[2 * i] = pk(u.x, u.y);
    wv1[2 * i + 1] = pk(u.z, u.w);
  }
#pragma unroll
  for (int i = 0; i < 8; ++i) {         // last 16 float4 per row -> LDS
    float4 a = w0p[48 + 2 * i], b = w0p[49 + 2 * i];
    lw4[i][tid] = make_uint4(pk(a.x, a.y), pk(a.z, a.w), pk(b.x, b.y), pk(b.z, b.w));
    float4 c4 = w1p[48 + 2 * i], d4 = w1p[49 + 2 * i];
    lw4[8 + i][tid] = make_uint4(pk(c4.x, c4.y), pk(c4.z, c4.w), pk(d4.x, d4.y), pk(d4.z, d4.w));
  }

  if (tid < 32) ((uint4*)hbuf)[tid] = make_uint4(0, 0, 0, 0);
  float c = 0.f, hl = 0.f;
  const unsigned short* xwp = xW + (size_t)n * 512 * 1024;
  __syncthreads();

  for (int t = 0; t < 512; ++t) {
    unsigned short xu0 = xwp[t * 1024 + g0];   // issued early, used after dots
    unsigned short xu1 = xwp[t * 1024 + g1];
    float a0 = b0, a1 = b1;
    // one 8B LDS read per lane: whole h vector distributed across the wave
    const uint2 hv = ((const uint2*)hbuf)[lane];
#pragma unroll
    for (int q = 0; q < 24; ++q) {             // VGPR-resident part (k 0..191)
      // h-dwords 4q..4q+3 -> lanes 2q (x,y), 2q+1 (x,y)
      const unsigned s0 = rlane(hv.x, 2 * q);
      const unsigned s1 = rlane(hv.y, 2 * q);
      const unsigned s2 = rlane(hv.x, 2 * q + 1);
      const unsigned s3 = rlane(hv.y, 2 * q + 1);
      a0 = fdot2(wv0[4 * q + 0], s0, a0); a1 = fdot2(wv1[4 * q + 0], s0, a1);
      a0 = fdot2(wv0[4 * q + 1], s1, a0); a1 = fdot2(wv1[4 * q + 1], s1, a1);
      a0 = fdot2(wv0[4 * q + 2], s2, a0); a1 = fdot2(wv1[4 * q + 2], s2, a1);
      a0 = fdot2(wv0[4 * q + 3], s3, a0); a1 = fdot2(wv1[4 * q + 3], s3, a1);
    }
#pragma unroll
    for (int q = 0; q < 8; ++q) {              // LDS-resident part (k 192..255)
      uint4 u0 = lw4[q][tid], u1 = lw4[8 + q][tid];
      // h-dwords 96+4q..99+4q -> lanes 48+2q (x,y), 49+2q (x,y)
      const int l0 = 48 + 2 * q;
      const unsigned s0 = rlane(hv.x, l0);
      const unsigned s1 = rlane(hv.y, l0);
      const unsigned s2 = rlane(hv.x, l0 + 1);
      const unsigned s3 = rlane(hv.y, l0 + 1);
      a0 = fdot2(u0.x, s0, a0); a1 = fdot2(u1.x, s0, a1);
      a0 = fdot2(u0.y, s1, a0); a1 = fdot2(u1.y, s1, a1);
      a0 = fdot2(u0.z, s2, a0); a1 = fdot2(u1.z, s2, a1);
      a0 = fdot2(u0.w, s3, a0); a1 = fdot2(u1.w, s3, a1);
    }
    a0 += h2f(xu0);
    a1 += h2f(xu1);

    float iact = 0.f, gact = 0.f;
    if (tid < 256) {                 // waves 0-3: i and g gates
      iact = sigmf(a0);
      gact = tanh_(a1);
    } else {                         // waves 4-7: f and o gates
      fBuf[tid - 256] = sigmf(a0);
      oBuf[tid - 256] = sigmf(a1);
    }
    __syncthreads();                 // f/o visible; all h reads done
    if (tid < 256) {
      c = fBuf[tid] * c + iact * gact;
      hl = oBuf[tid] * tanh_(c);
      hbuf[tid] = f2h(hl);
    }
    __syncthreads();                 // h(t) ready for step t+1
    if (WRITE_HS && tid < 128)
      hs[((size_t)n * 512 + t) * 128 + tid] = ((const unsigned*)hbuf)[tid];
  }

  if (FINAL) {
    if (tid < 256) fBuf[tid] = hl;
    __syncthreads();
    if (tid < 64) {
      float s = fBuf[tid] + fBuf[tid + 64] + fBuf[tid + 128] + fBuf[tid + 192];
      for (int off = 32; off > 0; off >>= 1) s += __shfl_down(s, off, 64);
      if (tid == 0) redBuf[0] = s * (1.f / 256.f);
    }
    __syncthreads();
    float mu = redBuf[0];
    if (tid < 256) oBuf[tid] = (hl - mu) * (hl - mu);
    __syncthreads();
    if (tid < 64) {
      float s = oBuf[tid] + oBuf[tid + 64] + oBuf[tid + 128] + oBuf[tid + 192];
      for (int off = 32; off > 0; off >>= 1) s += __shfl_down(s, off, 64);
      if (tid == 0) redBuf[1] = s * (1.f / 256.f);
    }
    __syncthreads();
    if (tid < 256) {
      float var = redBuf[1];
      out[(size_t)n * 256 + tid] =
          (hl - mu) * rsqrtf(var + 1e-5f) * gamma[tid] + beta[tid];
    }
  }
}

extern "C" void kernel_launch(void* const* d_in, const int* in_sizes, int n_in,
                              void* d_out, int out_size, void* d_ws, size_t ws_size,
                              hipStream_t stream) {
  const float* x     = (const float*)d_in[0];
  const float* Wih0  = (const float*)d_in[1];
  const float* Whh0  = (const float*)d_in[2];
  const float* bih0  = (const float*)d_in[3];
  const float* bhh0  = (const float*)d_in[4];
  const float* Wih1  = (const float*)d_in[5];
  const float* Whh1  = (const float*)d_in[6];
  const float* bih1  = (const float*)d_in[7];
  const float* bhh1  = (const float*)d_in[8];
  const float* gamma = (const float*)d_in[9];
  const float* beta  = (const float*)d_in[10];
  float* out = (float*)d_out;

  // workspace: xW buffer 128 MiB (reused for xW0 then xW1), hs0 32 MiB
  unsigned short* xw  = (unsigned short*)d_ws;
  unsigned short* hs0 = (unsigned short*)((char*)d_ws + (size_t)134217728);

  // layer 0 input projection: xW0 = x @ Wih0^T  (K=32)
  gemm_xw<32, 32, false><<<dim3(32, 128), 256, 0, stream>>>(x, Wih0, xw);
  // layer 0 recurrence -> hs0 (f16)
  lstm_rec<true, false><<<128, 512, 0, stream>>>(xw, Whh0, bih0, bhh0,
                                                 (unsigned*)hs0, nullptr, nullptr,
                                                 nullptr);
  // layer 1 input projection: xW1 = hs0 @ Wih1^T  (K=256)
  gemm_xw<256, 128, true><<<dim3(32, 128), 256, 0, stream>>>(hs0, Wih1, xw);
  // layer 1 recurrence + fused LayerNorm -> out
  lstm_rec<false, true><<<128, 512, 0, stream>>>(xw, Whh1, bih1, bhh1, nullptr,
                                                 gamma, beta, out);
}